// Round 4
// baseline (1360.614 us; speedup 1.0000x reference)
//
#include <hip/hip_runtime.h>
#include <hip/hip_fp16.h>
#include <hip/hip_cooperative_groups.h>

namespace cg = cooperative_groups;

// Problem constants
#define NV    884736     // 96^3 voxels
#define NB    3456       // NV / 256
#define DIM   96
#define DIM2  9216       // 96*96
#define NF    6          // fields needed: pos1,pos2,pos3,neg0,neg1,neg2
#define NSTEPS 7
#define SLACK 32         // uint2 pad entries after each buffer (zeroed in init)

// Cooperative integrate kernel geometry
#define STEP_W  (NB * NF)        // 20736 work units (1 unit = 256 voxels of one field)
#define GRID_I  864              // blocks; 864*24 = 20736; <=4 blocks/CU -> co-resident
#define UPB     24               // units per block per phase
#define XCHK    (STEP_W / 8)     // 2592 contiguous units per XCD

// Intermediate fields stored as half4 (x,y,z,pad) = 8 B/voxel.
// A z-adjacent voxel PAIR is 16 contiguous bytes -> one dwordx4 gather
// covers both z-corners of a trilinear cell. 4 gathers/sample, not 8.
//
// ONLY 6 of the 8 integrated fields are consumed by the loss:
//   F_pos[flo], flo in {1,2,3}  -> fields 0,1,2
//   F_neg[ref], ref in {0,1,2}  -> fields 3,4,5
//
// Round-3 lesson: per-step time = ~22 us fixed + ~3 us/field. The fixed part
// is the launch/drain boundary (7 ping-pong launches, each draining ~83K waves
// + re-warming L2). Fix: ONE cooperative kernel, grid.sync() between phases,
// each block keeps the SAME XCD-chunked slab across all phases (warm L2).

union H4 { uint2 u; __half2 h2[2]; };   // one voxel (8 B)
union H8 { uint4 u; __half2 h2[4]; };   // two z-adjacent voxels (16 B)

struct F3 { float x, y, z; };

__device__ __forceinline__ F3 lerp3(F3 a, F3 b, float t, float omt) {
    F3 r;
    r.x = a.x * omt + b.x * t;
    r.y = a.y * omt + b.y * t;
    r.z = a.z * omt + b.z * t;
    return r;
}

__device__ __forceinline__ uint2 pack_h4(float x, float y, float z) {
    H4 v;
    v.h2[0] = __floats2half2_rn(x, y);
    v.h2[1] = __floats2half2_rn(z, 0.0f);
    return v.u;
}

__device__ __forceinline__ F3 unpack_h4(uint2 raw) {
    H4 v; v.u = raw;
    float2 xy = __half22float2(v.h2[0]);
    float2 zp = __half22float2(v.h2[1]);
    F3 r; r.x = xy.x; r.y = xy.y; r.z = zp.x;
    return r;
}

// Phase-split trilinear sampling on half4 fields.
// Border semantics EXACTLY as the reference:
//   x0 = clamp((int)floor(x),0,95); x1 = min(x0+1,95); fx = x - floor(x) (unclamped)
// z edge: when z0==95 we'd need c001==c000; instead force fz=0 so the second
// voxel of the 16B pair (next row / zeroed pad) is multiplied by 0.
struct TriIdx { int idx[4]; float fx, fy, fz; };

__device__ __forceinline__ TriIdx tri_prep(float x, float y, float z) {
    TriIdx t;
    float xf = floorf(x), yf = floorf(y), zf = floorf(z);
    t.fx = x - xf; t.fy = y - yf;
    float fz = z - zf;
    int x0 = (int)xf; x0 = x0 < 0 ? 0 : (x0 > DIM - 1 ? DIM - 1 : x0);
    int y0 = (int)yf; y0 = y0 < 0 ? 0 : (y0 > DIM - 1 ? DIM - 1 : y0);
    int z0 = (int)zf; z0 = z0 < 0 ? 0 : (z0 > DIM - 1 ? DIM - 1 : z0);
    int x1 = x0 + 1; if (x1 > DIM - 1) x1 = DIM - 1;
    int y1 = y0 + 1; if (y1 > DIM - 1) y1 = DIM - 1;
    t.fz = (z0 < DIM - 1) ? fz : 0.0f;
    int X0 = x0 * DIM2, X1 = x1 * DIM2;
    int Y0 = y0 * DIM,  Y1 = y1 * DIM;
    t.idx[0] = X0 + Y0 + z0;   // c00* pair
    t.idx[1] = X0 + Y1 + z0;   // c01* pair
    t.idx[2] = X1 + Y0 + z0;   // c10* pair
    t.idx[3] = X1 + Y1 + z0;   // c11* pair
    return t;
}

__device__ __forceinline__ void tri_gather(const uint2* __restrict__ f,
                                           const TriIdx& t, H8 c[4]) {
    #pragma unroll
    for (int q = 0; q < 4; q++)
        c[q].u = *(const uint4*)(f + t.idx[q]);   // 16B: voxels z0, z0+1
}

__device__ __forceinline__ F3 tri_combine(const TriIdx& t, const H8 c[4]) {
    float gz = 1.0f - t.fz, gy = 1.0f - t.fy, gx = 1.0f - t.fx;
    F3 pz[4];
    #pragma unroll
    for (int q = 0; q < 4; q++) {
        float2 xy0 = __half22float2(c[q].h2[0]);
        float2 z0p = __half22float2(c[q].h2[1]);
        float2 xy1 = __half22float2(c[q].h2[2]);
        float2 z1p = __half22float2(c[q].h2[3]);
        F3 lo; lo.x = xy0.x; lo.y = xy0.y; lo.z = z0p.x;
        F3 hi; hi.x = xy1.x; hi.y = xy1.y; hi.z = z1p.x;
        pz[q] = lerp3(lo, hi, t.fz, gz);
    }
    F3 c0 = lerp3(pz[0], pz[1], t.fy, gy);
    F3 c1 = lerp3(pz[2], pz[3], t.fy, gy);
    return lerp3(c0, c1, t.fx, gx);
}

// Persistent cooperative kernel: init (v0 = +/-T/128) then 7 scaling-and-
// squaring steps, grid.sync() between phases. Block b owns the contiguous
// unit range [w0, w0+UPB) of the (field, voxel-block) work list for ALL
// phases; ranges are XCD-chunked (XCD x covers [x*XCHK,(x+1)*XCHK)).
__global__ __launch_bounds__(256, 4) void integrate_kernel(const float* __restrict__ T,
                                                           uint2* __restrict__ bufA,
                                                           uint2* __restrict__ bufB,
                                                           float* __restrict__ out) {
    cg::grid_group grid = cg::this_grid();
    const int tid = threadIdx.x;
    const int b   = blockIdx.x;
    const int w0  = (b & 7) * XCHK + (b >> 3) * UPB;

    // ---- init phase ----
    if (b == 0 && tid == 0) out[0] = 0.0f;
    if (b == 0 && tid < SLACK) {
        bufA[(size_t)NF * NV + tid] = make_uint2(0u, 0u);
        bufB[(size_t)NF * NV + tid] = make_uint2(0u, 0u);
    }
    const float inv = 1.0f / 128.0f;
    #pragma unroll 2
    for (int u = 0; u < UPB; u++) {
        int w  = w0 + u;
        int f  = w / NB;
        int vb = w - f * NB;
        int l  = vb * 256 + tid;
        int tr = (f < 3) ? (f + 1) : (f - 3);
        float sg = (f < 3) ? inv : -inv;
        float vx = T[(size_t)(tr * 3 + 0) * NV + l] * sg;
        float vy = T[(size_t)(tr * 3 + 1) * NV + l] * sg;
        float vz = T[(size_t)(tr * 3 + 2) * NV + l] * sg;
        bufA[(size_t)f * NV + l] = pack_h4(vx, vy, vz);
    }
    grid.sync();

    // ---- 7 steps, ping-pong ----
    uint2* src = bufA;
    uint2* dst = bufB;
    for (int s = 0; s < NSTEPS; s++) {
        #pragma unroll 2
        for (int u = 0; u < UPB; u++) {
            int w  = w0 + u;
            int f  = w / NB;
            int vb = w - f * NB;
            int l  = vb * 256 + tid;
            const uint2* __restrict__ sp = src + (size_t)f * NV;
            int i   = l / DIM2;
            int rem = l - i * DIM2;
            int j   = rem / DIM;
            int k   = rem - j * DIM;
            F3 v = unpack_h4(sp[l]);
            TriIdx tt = tri_prep((float)i + v.x, (float)j + v.y, (float)k + v.z);
            H8 c[4];
            tri_gather(sp, tt, c);
            F3 smp = tri_combine(tt, c);
            dst[(size_t)f * NV + l] = pack_h4(v.x + smp.x, v.y + smp.y, v.z + smp.z);
        }
        grid.sync();
        uint2* tmp = src; src = dst; dst = tmp;
    }
    // NSTEPS=7 (odd): final fields live in bufB.
}

// Compose + residual + loss. Pair-pair split: 3x the blocks of round-3 for
// 3x wave parallelism (the latency-hiding currency), same 2-pairs-per-thread
// in-flight state (round-1 showed 3 pairs in flight thrashes L2).
//   pp=0: pairs {0,1}  refs {0,0}  flo fields {0,1}
//   pp=1: pairs {2,3}  refs {0,1}  flo fields {2,1}
//   pp=2: pairs {4,5}  refs {1,2}  flo fields {2,2}
#define NBL3 (NB * 3)            // 10368 blocks
#define LCHK (NBL3 / 8)          // 1296 per XCD
__global__ __launch_bounds__(256) void loss_kernel(const uint2* __restrict__ fields,
                                                   const float* __restrict__ R,
                                                   float* __restrict__ out) {
    int b  = blockIdx.x;
    int wl = (b & 7) * LCHK + (b >> 3);   // bijective XCD-chunked swizzle
    int pp = wl / NB;
    int vb = wl - pp * NB;
    int l  = vb * 256 + threadIdx.x;
    int k = l % DIM;
    int j = (l / DIM) % DIM;
    int i = l / DIM2;
    float fi = (float)i, fj = (float)j, fk = (float)k;

    int p0 = pp * 2, p1 = p0 + 1;
    int refa = pp >> 1, refb = pp;                 // f1 = fields 3+ref
    int floa = pp ? 2 : 0, flob = 1 + (pp >> 1);   // f2 = fields flo

    // R is (96,96,96,3,6): 18 floats/voxel; channel c, pair p at l*18 + c*6 + p.
    const float* Rl = R + (size_t)l * 18;
    float ra_x = Rl[0 * 6 + p0], ra_y = Rl[1 * 6 + p0], ra_z = Rl[2 * 6 + p0];
    float rb_x = Rl[0 * 6 + p1], rb_y = Rl[1 * 6 + p1], rb_z = Rl[2 * 6 + p1];

    F3 f1a = unpack_h4(fields[(size_t)(3 + refa) * NV + l]);
    F3 f1b = unpack_h4(fields[(size_t)(3 + refb) * NV + l]);
    const uint2* __restrict__ f2a = fields + (size_t)floa * NV;
    const uint2* __restrict__ f2b = fields + (size_t)flob * NV;

    TriIdx ta = tri_prep(fi + f1a.x, fj + f1a.y, fk + f1a.z);
    TriIdx tb = tri_prep(fi + f1b.x, fj + f1b.y, fk + f1b.z);
    H8 ca[4], cb[4];
    tri_gather(f2a, ta, ca);
    tri_gather(f2b, tb, cb);
    F3 sa = tri_combine(ta, ca);
    F3 sb = tri_combine(tb, cb);

    float rx = f1a.x + sa.x - ra_x;
    float ry = f1a.y + sa.y - ra_y;
    float rz = f1a.z + sa.z - ra_z;
    float acc = sqrtf(rx * rx + ry * ry + rz * rz);
    rx = f1b.x + sb.x - rb_x;
    ry = f1b.y + sb.y - rb_y;
    rz = f1b.z + sb.z - rb_z;
    acc += sqrtf(rx * rx + ry * ry + rz * rz);

    // Block reduction: wave64 shuffle, then LDS across 4 waves, one atomic per block.
    __shared__ float wsum[4];
    int lane = threadIdx.x & 63;
    int wid  = threadIdx.x >> 6;
    #pragma unroll
    for (int off = 32; off > 0; off >>= 1)
        acc += __shfl_down(acc, off, 64);
    if (lane == 0) wsum[wid] = acc;
    __syncthreads();
    if (threadIdx.x == 0) {
        float s = wsum[0] + wsum[1] + wsum[2] + wsum[3];
        atomicAdd(out, s);
    }
}

extern "C" void kernel_launch(void* const* d_in, const int* in_sizes, int n_in,
                              void* d_out, int out_size, void* d_ws, size_t ws_size,
                              hipStream_t stream) {
    const float* T = (const float*)d_in[0];   // (4,3,96,96,96) fp32
    const float* R = (const float*)d_in[1];   // (96,96,96,3,6) fp32
    float* out = (float*)d_out;               // scalar loss

    // Workspace: two ping-pong buffers of 6 half4 fields.
    // Each buffer: 6 * 884736 * 8 B = 42.5 MB; +SLACK uint2 pad (zeroed) for
    // the 16B pair-gather that can read 8B past the last voxel.
    uint2* bufA = (uint2*)d_ws;
    uint2* bufB = bufA + (size_t)NF * NV + SLACK;

    void* args[] = { (void*)&T, (void*)&bufA, (void*)&bufB, (void*)&out };
    hipLaunchCooperativeKernel((const void*)integrate_kernel,
                               dim3(GRID_I), dim3(256), args, 0, stream);

    // Final fields in bufB (7 = odd number of ping-pong steps).
    loss_kernel<<<NBL3, dim3(256), 0, stream>>>(bufB, R, out);
}

// Round 5
// 349.606 us; speedup vs baseline: 3.8918x; 3.8918x over previous
//
#include <hip/hip_runtime.h>
#include <hip/hip_fp16.h>

// Problem constants
#define NV    884736     // 96^3 voxels
#define NB    3456       // NV / 256
#define DIM   96
#define DIM2  9216       // 96*96
#define NF    6          // fields actually needed: pos1,pos2,pos3,neg0,neg1,neg2
#define SLACK 32         // uint2 pad entries after each buffer (zeroed in init)

// Intermediate fields stored as half4 (x,y,z,pad) = 8 B/voxel.
// A z-adjacent voxel PAIR is 16 contiguous bytes -> one dwordx4 gather
// covers both z-corners of a trilinear cell. 4 gathers/sample, not 8.
//
// ONLY 6 of the 8 integrated fields are consumed by the loss:
//   F_pos[flo], flo in {1,2,3}  -> fields 0,1,2
//   F_neg[ref], ref in {0,1,2}  -> fields 3,4,5
//
// Cost model (fits rounds 0-4): the vector-memory address pipe handles ~1
// divergent lane-address/cycle/CU. Step: 4 gathers x 64 addr = 256 addr-cy
// per wave -> 34.5 us/step floor (observed 40). Loss: gathers 512 addr-cy
// PLUS 18 stride-72B R reads = 1152 addr-cy -> that R term is removable by
// LDS staging (coalesced float4 in, ds_read out). Round-4 lesson: persistent
// per-thread work loops make the compiler serialize gathers (VGPR=32, 4x
// slower) -- keep one-unit-per-thread kernels.

union H4 { uint2 u; __half2 h2[2]; };   // one voxel (8 B)
union H8 { uint4 u; __half2 h2[4]; };   // two z-adjacent voxels (16 B)

struct F3 { float x, y, z; };

__device__ __forceinline__ F3 lerp3(F3 a, F3 b, float t, float omt) {
    F3 r;
    r.x = a.x * omt + b.x * t;
    r.y = a.y * omt + b.y * t;
    r.z = a.z * omt + b.z * t;
    return r;
}

__device__ __forceinline__ uint2 pack_h4(float x, float y, float z) {
    H4 v;
    v.h2[0] = __floats2half2_rn(x, y);
    v.h2[1] = __floats2half2_rn(z, 0.0f);
    return v.u;
}

__device__ __forceinline__ F3 unpack_h4(uint2 raw) {
    H4 v; v.u = raw;
    float2 xy = __half22float2(v.h2[0]);
    float2 zp = __half22float2(v.h2[1]);
    F3 r; r.x = xy.x; r.y = xy.y; r.z = zp.x;
    return r;
}

// Phase-split trilinear sampling on half4 fields.
// Border semantics EXACTLY as the reference:
//   x0 = clamp((int)floor(x),0,95); x1 = min(x0+1,95); fx = x - floor(x) (unclamped)
// z edge: when z0==95 we'd need c001==c000; instead force fz=0 so the second
// voxel of the 16B pair (next row / zeroed pad) is multiplied by 0.
struct TriIdx { int idx[4]; float fx, fy, fz; };

__device__ __forceinline__ TriIdx tri_prep(float x, float y, float z) {
    TriIdx t;
    float xf = floorf(x), yf = floorf(y), zf = floorf(z);
    t.fx = x - xf; t.fy = y - yf;
    float fz = z - zf;
    int x0 = (int)xf; x0 = x0 < 0 ? 0 : (x0 > DIM - 1 ? DIM - 1 : x0);
    int y0 = (int)yf; y0 = y0 < 0 ? 0 : (y0 > DIM - 1 ? DIM - 1 : y0);
    int z0 = (int)zf; z0 = z0 < 0 ? 0 : (z0 > DIM - 1 ? DIM - 1 : z0);
    int x1 = x0 + 1; if (x1 > DIM - 1) x1 = DIM - 1;
    int y1 = y0 + 1; if (y1 > DIM - 1) y1 = DIM - 1;
    t.fz = (z0 < DIM - 1) ? fz : 0.0f;
    int X0 = x0 * DIM2, X1 = x1 * DIM2;
    int Y0 = y0 * DIM,  Y1 = y1 * DIM;
    t.idx[0] = X0 + Y0 + z0;   // c00* pair
    t.idx[1] = X0 + Y1 + z0;   // c01* pair
    t.idx[2] = X1 + Y0 + z0;   // c10* pair
    t.idx[3] = X1 + Y1 + z0;   // c11* pair
    return t;
}

__device__ __forceinline__ void tri_gather(const uint2* __restrict__ f,
                                           const TriIdx& t, H8 c[4]) {
    #pragma unroll
    for (int q = 0; q < 4; q++)
        c[q].u = *(const uint4*)(f + t.idx[q]);   // 16B: voxels z0, z0+1
}

__device__ __forceinline__ F3 tri_combine(const TriIdx& t, const H8 c[4]) {
    float gz = 1.0f - t.fz, gy = 1.0f - t.fy, gx = 1.0f - t.fx;
    F3 pz[4];
    #pragma unroll
    for (int q = 0; q < 4; q++) {
        float2 xy0 = __half22float2(c[q].h2[0]);
        float2 z0p = __half22float2(c[q].h2[1]);
        float2 xy1 = __half22float2(c[q].h2[2]);
        float2 z1p = __half22float2(c[q].h2[3]);
        F3 lo; lo.x = xy0.x; lo.y = xy0.y; lo.z = z0p.x;
        F3 hi; hi.x = xy1.x; hi.y = xy1.y; hi.z = z1p.x;
        pz[q] = lerp3(lo, hi, t.fz, gz);
    }
    F3 c0 = lerp3(pz[0], pz[1], t.fy, gy);
    F3 c1 = lerp3(pz[2], pz[3], t.fy, gy);
    return lerp3(c0, c1, t.fx, gx);
}

// Init: v0 = +T/128 for transforms 1..3 -> fields 0..2,
//       v0 = -T/128 for transforms 0..2 -> fields 3..5.
// Also zeroes the loss accumulator and the 16B-overread pad of both buffers.
__global__ __launch_bounds__(256) void init_kernel(const float* __restrict__ T,
                                                   uint2* __restrict__ bufA,
                                                   uint2* __restrict__ bufB,
                                                   float* __restrict__ out) {
    int t = blockIdx.y;                       // transform 0..3
    int l = blockIdx.x * 256 + threadIdx.x;   // voxel linear index
    if (t == 0 && l == 0) out[0] = 0.0f;
    if (t == 0 && l < SLACK) {
        bufA[(size_t)NF * NV + l] = make_uint2(0u, 0u);
        bufB[(size_t)NF * NV + l] = make_uint2(0u, 0u);
    }
    const float inv = 1.0f / 128.0f;
    float vx = T[(size_t)(t * 3 + 0) * NV + l] * inv;
    float vy = T[(size_t)(t * 3 + 1) * NV + l] * inv;
    float vz = T[(size_t)(t * 3 + 2) * NV + l] * inv;
    if (t >= 1) bufA[(size_t)(t - 1) * NV + l] = pack_h4( vx,  vy,  vz);
    if (t <= 2) bufA[(size_t)(t + 3) * NV + l] = pack_h4(-vx, -vy, -vz);
}

// One scaling-and-squaring step for the 6 live fields (round-3 proven form:
// VPT=1, one unit per thread, XCD-chunked bijective swizzle).
#define STEP_VB   NB                      // 3456 voxel-blocks per field
#define STEP_W    (STEP_VB * NF)          // 20736 work units
#define STEP_CHK  (STEP_W / 8)            // 2592 per XCD
__global__ __launch_bounds__(256) void step_kernel(const uint2* __restrict__ src,
                                                   uint2* __restrict__ dst) {
    int b   = blockIdx.x;
    int w   = (b & 7) * STEP_CHK + (b >> 3);
    int f   = w / STEP_VB;
    int vb  = w - f * STEP_VB;
    const uint2* __restrict__ s = src + (size_t)f * NV;
    uint2*       __restrict__ d = dst + (size_t)f * NV;

    int l   = vb * 256 + threadIdx.x;
    int i   = l / DIM2;
    int rem = l - i * DIM2;
    int j   = rem / DIM;
    int k   = rem - j * DIM;

    F3 v = unpack_h4(s[l]);
    TriIdx t = tri_prep((float)i + v.x, (float)j + v.y, (float)k + v.z);
    H8 c[4];
    tri_gather(s, t, c);
    F3 smp = tri_combine(t, c);
    d[l] = pack_h4(v.x + smp.x, v.y + smp.y, v.z + smp.z);
}

// Compose + residual + loss for all 6 pairs, one thread per voxel,
// two pairs in flight. R reads (18 floats at stride 72B = fully divergent,
// 1152 addr-cy/wave on the TA pipe) are replaced by PER-WAVE LDS staging:
// coalesced float4 loads (288 per wave region) + ds_read_b64 readback.
// Per-wave region -> no __syncthreads (no vmcnt(0) drain of the gathers).
__global__ __launch_bounds__(256) void loss_kernel(const uint2* __restrict__ fields,
                                                   const float* __restrict__ R,
                                                   float* __restrict__ out) {
    __shared__ float rlds[4 * 1152];          // 4 waves x 64 voxels x 18 floats = 18 KB
    int b = blockIdx.x;
    int vb = (b & 7) * (NB / 8) + (b >> 3);   // bijective XCD-chunked swizzle
    int l = vb * 256 + threadIdx.x;
    int lane = threadIdx.x & 63;
    int wid  = threadIdx.x >> 6;

    // Stage this wave's 64 voxels of R: 1152 floats = 288 float4, coalesced.
    // Base (vb*256 + wid*64)*18 floats = multiple of 4608B -> 16B aligned.
    {
        const float4* Rw = (const float4*)(R + ((size_t)vb * 256 + wid * 64) * 18);
        float4* lw = (float4*)(rlds + wid * 1152);
        #pragma unroll
        for (int q = 0; q < 5; q++) {
            int idx = q * 64 + lane;
            if (idx < 288) lw[idx] = Rw[idx];
        }
    }
    float* myR = rlds + wid * 1152 + lane * 18;   // this thread's 18 floats

    int k = l % DIM;
    int j = (l / DIM) % DIM;
    int i = l / DIM2;
    float fi = (float)i, fj = (float)j, fk = (float)k;

    // F_neg for ref indices 0,1,2 -> fields 3,4,5 (coalesced 8B loads)
    F3 f1c[3];
    #pragma unroll
    for (int r = 0; r < 3; r++)
        f1c[r] = unpack_h4(fields[(size_t)(3 + r) * NV + l]);

    const int REFI[6] = {0, 0, 0, 1, 1, 2};   // -> f1c index
    const int FLOF[6] = {0, 1, 2, 1, 2, 2};   // F_pos[flo] -> field flo-1

    float acc = 0.0f;
    #pragma unroll
    for (int p = 0; p < 6; p += 2) {
        F3 f1a = f1c[REFI[p]];
        F3 f1b = f1c[REFI[p + 1]];
        const uint2* __restrict__ f2a = fields + (size_t)FLOF[p]     * NV;
        const uint2* __restrict__ f2b = fields + (size_t)FLOF[p + 1] * NV;
        TriIdx ta = tri_prep(fi + f1a.x, fj + f1a.y, fk + f1a.z);
        TriIdx tb = tri_prep(fi + f1b.x, fj + f1b.y, fk + f1b.z);
        H8 ca[4], cb[4];
        tri_gather(f2a, ta, ca);
        tri_gather(f2b, tb, cb);
        // R for pairs p,p+1: channel c at myR[c*6 + p] -- adjacent floats,
        // 8B aligned (lane*18 + c*6 + p all even) -> ds_read_b64 each.
        float2 rx2 = *(const float2*)(myR + 0 * 6 + p);
        float2 ry2 = *(const float2*)(myR + 1 * 6 + p);
        float2 rz2 = *(const float2*)(myR + 2 * 6 + p);
        F3 sa = tri_combine(ta, ca);
        F3 sb = tri_combine(tb, cb);
        float rx = f1a.x + sa.x - rx2.x;
        float ry = f1a.y + sa.y - ry2.x;
        float rz = f1a.z + sa.z - rz2.x;
        acc += sqrtf(rx * rx + ry * ry + rz * rz);
        rx = f1b.x + sb.x - rx2.y;
        ry = f1b.y + sb.y - ry2.y;
        rz = f1b.z + sb.z - rz2.y;
        acc += sqrtf(rx * rx + ry * ry + rz * rz);
    }

    // Block reduction: wave64 shuffle, then LDS across 4 waves, one atomic per block.
    __shared__ float wsum[4];
    #pragma unroll
    for (int off = 32; off > 0; off >>= 1)
        acc += __shfl_down(acc, off, 64);
    if (lane == 0) wsum[wid] = acc;
    __syncthreads();
    if (threadIdx.x == 0) {
        float s = wsum[0] + wsum[1] + wsum[2] + wsum[3];
        atomicAdd(out, s);
    }
}

extern "C" void kernel_launch(void* const* d_in, const int* in_sizes, int n_in,
                              void* d_out, int out_size, void* d_ws, size_t ws_size,
                              hipStream_t stream) {
    const float* T = (const float*)d_in[0];   // (4,3,96,96,96) fp32
    const float* R = (const float*)d_in[1];   // (96,96,96,3,6) fp32
    float* out = (float*)d_out;               // scalar loss

    // Workspace: two ping-pong buffers of 6 half4 fields.
    // Each buffer: 6 * 884736 * 8 B = 42.5 MB; +SLACK uint2 pad (zeroed) for
    // the 16B pair-gather that can read 8B past the last voxel.
    uint2* bufA = (uint2*)d_ws;
    uint2* bufB = bufA + (size_t)NF * NV + SLACK;

    dim3 blk(256);
    init_kernel<<<dim3(NB, 4), blk, 0, stream>>>(T, bufA, bufB, out);

    uint2* src = bufA;
    uint2* dst = bufB;
    for (int s = 0; s < 7; s++) {
        step_kernel<<<STEP_W, blk, 0, stream>>>(src, dst);
        uint2* tmp = src; src = dst; dst = tmp;
    }
    // After 7 steps (odd), final fields are in bufB == src.
    loss_kernel<<<NB, blk, 0, stream>>>(src, R, out);
}